// Round 6
// baseline (56.155 us; speedup 1.0000x reference)
//
#include <hip/hip_runtime.h>

#define NORB   12
#define NFEAT  14
#define NCOL1  144
#define NCOL2  20736
#define RPB    192          // threads per block
#define NSPLIT 9            // two-body chunks per sample (9*192 = 1728 rows)
#define CPS    (NSPLIT + 1) // blocks per sample (chunk 0 = prep)
#define NT     256          // samples
#define GRID   (NT * CPS)

// ---------------- single fused kernel ----------------
extern "C" __global__ void __launch_bounds__(RPB)
eloc_one(const float* __restrict__ mfv, const float* __restrict__ h1,
         const float* __restrict__ h2, const int* __restrict__ vn,
         const float* __restrict__ w,
         double* __restrict__ ep, double* __restrict__ e2acc,
         unsigned* __restrict__ ctr, float* __restrict__ out)
{
    const int tid = threadIdx.x;
    const int bid = blockIdx.x;
    const int t   = bid / CPS;
    const int ch  = bid % CPS;

    // shared: prep branch + finisher
    __shared__ float phi_s[NORB][NFEAT];
    __shared__ int   x_s[NORB];
    __shared__ float W_s[NFEAT][NFEAT];
    __shared__ float tmp_s[NORB][NFEAT];
    __shared__ float G_s[NORB][NORB];
    __shared__ unsigned char m1_s[NCOL1];
    __shared__ int Ri_s[NORB], Rj_s[NORB], M_s;
    __shared__ double A1[NORB][NORB], A2[NORB][NORB];
    __shared__ double red_s[RPB / 64];
    __shared__ double det_s[2];
    __shared__ double h1sum_s;
    __shared__ double se_s[NT], sp_s[NT];
    __shared__ int last_s;

    if (ch != 0) {
        // ---------------- two-body: wave-autonomous, no LDS, no barriers ----------------
        const int lane = tid & 63;
        const int r = (ch - 1) * RPB + tid;             // 0..1727
        const int i = r / 144, j = (r / NORB) % NORB, p = r % NORB;

        const float4* hr = (const float4*)(h2 + (size_t)t * NCOL2 + (size_t)r * NORB);
        const float4 ha = hr[0], hb = hr[1], hc = hr[2];

        int   xv  = 1;
        float psl = 0.f;
        if (lane < NORB) {
            xv = vn[t * NORB + lane];
            const float* pr = mfv + (size_t)t * NORB * NFEAT + lane * NFEAT;
            float s = 0.f;
            #pragma unroll
            for (int f = 0; f < NFEAT; ++f) s += pr[f];
            psl = s;
        }
        const unsigned long long bal = __ballot(xv == 2);
        const int X2  = (int)(bal & 0xFFFull);
        const int nx2 = ~X2 & 0xFFF;

        float sv = (lane < NORB) ? psl * (float)xv : 0.f;
        sv += __shfl_xor(sv, 8, 16);
        sv += __shfl_xor(sv, 4, 16);
        sv += __shfl_xor(sv, 2, 16);
        sv += __shfl_xor(sv, 1, 16);
        const float Sv = __shfl(sv, 0, 64);

        float psv[NORB];
        #pragma unroll
        for (int q = 0; q < NORB; ++q) psv[q] = __shfl(psl, q, 64);

        const int bi = 1 << i, bj = 1 << j, bp = 1 << p;
        const int um0 = 0xFFF & ~(bi | bj | bp);
        const int xi = 1 + ((X2 >> i) & 1);
        const int xj = 1 + ((X2 >> j) & 1);
        const int xp = 1 + ((X2 >> p) & 1);
        const int basei = xi + 1 - ((bi >> j) & 1) - ((bi >> p) & 1);
        const int basej = xj + ((bj >> i) & 1) - 1 - ((bj >> p) & 1);
        const int basep = xp + ((bp >> i) & 1) - ((bp >> j) & 1) - 1;
        const float a2b = Sv + __shfl(psl, i, 64) - __shfl(psl, j, 64)
                        - __shfl(psl, p, 64);

        float acc = 0.f;
#define COLQ(q, hv) {                                                       \
        const int bq  = 1 << (q);                                           \
        const int um  = um0 & ~bq;                                          \
        const int hm1 = nx2 & um, hm2 = X2 & um;                            \
        int mn = hm1 ? 1 : (hm2 ? 2 : 9);                                   \
        int mx = hm2 ? 2 : (hm1 ? 1 : -9);                                  \
        const int iq = (bi >> (q)) & 1, jq = (bj >> (q)) & 1,               \
                  pq = (bp >> (q)) & 1;                                     \
        const int vi = basei + iq, vj = basej + jq, vp = basep + pq;        \
        const int xq = 1 + ((X2 >> (q)) & 1);                               \
        const int vq = xq + 1 + iq - jq - pq;                               \
        mn = min(min(mn, vi), min(vj, min(vp, vq)));                        \
        mx = max(max(mx, vi), max(vj, max(vp, vq)));                        \
        const bool ok = (mx - mn == 1) && ((hv) > 0.0f);                    \
        const float tq = ok ? (hv) * (a2b + psv[q]) : 0.0f;                 \
        acc = fmaf(tq, tq, acc);                                            \
    }
        COLQ(0,  ha.x)  COLQ(1,  ha.y)  COLQ(2,  ha.z)  COLQ(3,  ha.w)
        COLQ(4,  hb.x)  COLQ(5,  hb.y)  COLQ(6,  hb.z)  COLQ(7,  hb.w)
        COLQ(8,  hc.x)  COLQ(9,  hc.y)  COLQ(10, hc.z)  COLQ(11, hc.w)
#undef COLQ

        double accd = (double)acc;
        #pragma unroll
        for (int o = 32; o > 0; o >>= 1) accd += __shfl_down(accd, o, 64);
        if (lane == 0) atomicAdd(&e2acc[t], accd);   // device-scope, coherent point
    } else {
        // ---------------- prep: G, one-body, determinants (LDS path) ----------------
        if (tid < NORB * NFEAT)
            phi_s[tid / NFEAT][tid % NFEAT] = mfv[(size_t)t * NORB * NFEAT + tid];
        if (tid >= NORB * NFEAT && tid < NORB * NFEAT + NORB)
            x_s[tid - NORB * NFEAT] = vn[t * NORB + (tid - NORB * NFEAT)];
        for (int k2 = tid; k2 < NFEAT * NFEAT; k2 += RPB) {
            int r2 = k2 / NFEAT, c2 = k2 % NFEAT;
            W_s[r2][c2] = w[k2] + w[c2 * NFEAT + r2];
        }
        __syncthreads();

        int X2 = 0;
        #pragma unroll
        for (int a = 0; a < NORB; ++a) X2 |= (x_s[a] == 2) ? (1 << a) : 0;
        const int nx2 = ~X2 & 0xFFF;

        if (tid < NORB * NFEAT) {
            int a = tid / NFEAT, f = tid % NFEAT;
            float s = 0.f;
            #pragma unroll
            for (int g = 0; g < NFEAT; ++g) s += phi_s[a][g] * W_s[g][f];
            tmp_s[a][f] = s;
        }
        __syncthreads();
        if (tid < NCOL1) {
            int a = tid / NORB, i = tid % NORB;
            float s = 0.f;
            #pragma unroll
            for (int f = 0; f < NFEAT; ++f) s += tmp_s[a][f] * phi_s[i][f];
            G_s[a][i] = s;
        }

        // one-body mask + h1^2 sum
        double h1c = 0.0;
        if (tid < NCOL1) {
            int ii = tid / NORB, jj = tid % NORB;
            int um  = 0xFFF & ~((1 << ii) | (1 << jj));
            int hm1 = nx2 & um, hm2 = X2 & um;
            int mn = hm1 ? 1 : (hm2 ? 2 : 9);
            int mx = hm2 ? 2 : (hm1 ? 1 : -9);
            int d  = (ii == jj) ? 0 : 1;
            int vi = x_s[ii] - d, vj = x_s[jj] + d;
            mn = min(mn, min(vi, vj));
            mx = max(mx, max(vi, vj));
            float h1v = h1[(size_t)t * NCOL1 + tid];
            bool ok = (mx - mn == 1) && (h1v > 0.0f);
            m1_s[tid] = ok ? 1 : 0;
            if (ok) h1c = (double)h1v * (double)h1v;
        }
        __syncthreads();
        {
            #pragma unroll
            for (int o = 32; o > 0; o >>= 1) h1c += __shfl_down(h1c, o, 64);
            const int wvv = tid >> 6, lane = tid & 63;
            if (lane == 0) red_s[wvv] = h1c;
            __syncthreads();
            if (tid == 0) h1sum_s = red_s[0] + red_s[1] + red_s[2];
        }

        if (tid < NORB) {
            int ri = 0, rj = 0;
            #pragma unroll
            for (int o = 0; o < NORB; ++o) {
                ri += m1_s[tid * NORB + o];
                rj += m1_s[o * NORB + tid];
            }
            Ri_s[tid] = ri;
            Rj_s[tid] = rj;
        }
        __syncthreads();
        if (tid == 0) {
            int m = 0;
            #pragma unroll
            for (int o = 0; o < NORB; ++o) m += Ri_s[o];
            M_s = m;
        }
        __syncthreads();

        if (tid < NCOL1) {
            int a = tid / NORB, b = tid % NORB;
            int xa = x_s[a], xb = x_s[b];
            int Da = Rj_s[a] - Ri_s[a], Db = Rj_s[b] - Ri_s[b];
            int s1 = xa * xb * M_s + xa * Db + xb * Da
                   - (int)m1_s[b * NORB + a] - (int)m1_s[a * NORB + b];
            if (a == b) s1 += Rj_s[a] + Ri_s[a];
            A1[a][b] = (double)G_s[a][b] * (double)s1;
            A2[a][b] = (double)G_s[a][b];
        }
        __syncthreads();

        // barrier-free in-register LU with partial pivoting; wave0: A1, wave1: A2
        const int wvv = tid >> 6, lane = tid & 63;
        if (wvv < 2) {
            const double* Abase = (wvv == 0) ? &A1[0][0] : &A2[0][0];
            const int rl = (lane < NORB) ? lane : 0;
            double a[NORB];
            #pragma unroll
            for (int c = 0; c < NORB; ++c) a[c] = Abase[rl * NORB + c];
            double det = 1.0;
            #pragma unroll
            for (int k = 0; k < NORB; ++k) {
                double key = (lane >= k && lane < NORB) ? fabs(a[k]) : -1.0;
                int idx = lane;
                #pragma unroll
                for (int off = 8; off >= 1; off >>= 1) {
                    double k2 = __shfl_xor(key, off);
                    int    i2 = __shfl_xor(idx, off);
                    if (k2 > key || (k2 == key && i2 < idx)) { key = k2; idx = i2; }
                }
                int pr = idx;
                if (pr != k) det = -det;
                int src = (lane == k) ? pr : ((lane == pr) ? k : lane);
                #pragma unroll
                for (int c = 0; c < NORB; ++c) a[c] = __shfl(a[c], src);
                double pk[NORB];
                #pragma unroll
                for (int c = 0; c < NORB; ++c) pk[c] = __shfl(a[c], k);
                double piv = pk[k];
                det *= piv;
                double inv = (piv != 0.0) ? 1.0 / piv : 0.0;
                double f = (lane > k && lane < NORB) ? a[k] * inv : 0.0;
                #pragma unroll
                for (int c = 0; c < NORB; ++c) a[c] = fma(-f, pk[c], a[c]);
            }
            if (lane == 0) det_s[wvv] = det;
        }
        __syncthreads();

        if (tid == 0) {
            double e1 = det_s[0] * det_s[0] * h1sum_s;
            int n2 = __popc(X2);
            double pd = det_s[1] * (double)(1ull << (2 * n2));
            // agent-scope coherent stores (bypass non-coherent per-XCD L2)
            __hip_atomic_store(&ep[2 * t], e1, __ATOMIC_RELAXED, __HIP_MEMORY_SCOPE_AGENT);
            __hip_atomic_store(&ep[2 * t + 1], pd * pd, __ATOMIC_RELAXED, __HIP_MEMORY_SCOPE_AGENT);
        }
    }

    // ---------------- completion: fence-free finisher election ----------------
    // wait this wave's outstanding atomics (ack at coherence point); no cache flush
    asm volatile("s_waitcnt vmcnt(0)" ::: "memory");
    __syncthreads();   // all waves of this block have completed their atomics
    if (tid == 0) {
        unsigned old = __hip_atomic_fetch_add(ctr, 1u, __ATOMIC_RELAXED,
                                              __HIP_MEMORY_SCOPE_AGENT);
        last_s = (old == (unsigned)(GRID - 1)) ? 1 : 0;
    }
    __syncthreads();
    if (last_s) {
        for (int s2 = tid; s2 < NT; s2 += RPB) {
            double e2 = __hip_atomic_load(&e2acc[s2], __ATOMIC_RELAXED,
                                          __HIP_MEMORY_SCOPE_AGENT);
            double e1 = __hip_atomic_load(&ep[2 * s2], __ATOMIC_RELAXED,
                                          __HIP_MEMORY_SCOPE_AGENT);
            double p  = __hip_atomic_load(&ep[2 * s2 + 1], __ATOMIC_RELAXED,
                                          __HIP_MEMORY_SCOPE_AGENT);
            double e = e1 + e2;
            se_s[s2] = e * p;
            sp_s[s2] = p;
        }
        __syncthreads();
        if (tid < NT / 16) {
            double se = 0.0, sp = 0.0;
            #pragma unroll
            for (int u = 0; u < 16; ++u) {
                se += se_s[tid * 16 + u];
                sp += sp_s[tid * 16 + u];
            }
            out[tid] = (float)(se / sp);
        }
    }
}

extern "C" void kernel_launch(void* const* d_in, const int* in_sizes, int n_in,
                              void* d_out, int out_size, void* d_ws, size_t ws_size,
                              hipStream_t stream) {
    const float* mfv = (const float*)d_in[0];
    const float* h1  = (const float*)d_in[1];
    const float* h2  = (const float*)d_in[2];
    const int*   vn  = (const int*)d_in[3];
    const float* w   = (const float*)d_in[4];
    float* out = (float*)d_out;

    // ws layout: [ctr 8B][e2acc NT*8B]   (cleared each replay)
    //            [ep 2*NT*8B @ offset 4096] (fully overwritten each replay)
    unsigned* ctr   = (unsigned*)d_ws;
    double*   e2acc = (double*)((char*)d_ws + 8);
    double*   ep    = (double*)((char*)d_ws + 4096);

    hipMemsetAsync(d_ws, 0, 8 + NT * 8, stream);   // capture-legal memset node
    hipLaunchKernelGGL(eloc_one, dim3(GRID), dim3(RPB), 0, stream,
                       mfv, h1, h2, vn, w, ep, e2acc, ctr, out);
}

// Round 7
// 32.593 us; speedup vs baseline: 1.7229x; 1.7229x over previous
//
#include <hip/hip_runtime.h>

#define NORB   12
#define NFEAT  14
#define NCOL1  144
#define NCOL2  20736
#define RPB    192          // threads per block
#define NSPLIT 9            // two-body chunks per sample (9*192 = 1728 rows)
#define CPS    (NSPLIT + 1) // blocks per sample (chunk 0 = prep)
#define NT     256          // samples
#define NB     16           // batches
#define GRID   (NT * CPS)

// ---------------- single fused kernel, hierarchical finalize ----------------
extern "C" __global__ void __launch_bounds__(RPB)
eloc_one(const float* __restrict__ mfv, const float* __restrict__ h1,
         const float* __restrict__ h2, const int* __restrict__ vn,
         const float* __restrict__ w,
         unsigned* __restrict__ sctr, unsigned* __restrict__ bctr,
         double* __restrict__ e2acc, double* __restrict__ sb_e,
         double* __restrict__ sb_p, double* __restrict__ ep,
         float* __restrict__ out)
{
    const int tid = threadIdx.x;
    const int bid = blockIdx.x;
    const int t   = bid / CPS;
    const int ch  = bid % CPS;

    // shared: prep branch only
    __shared__ float phi_s[NORB][NFEAT];
    __shared__ int   x_s[NORB];
    __shared__ float W_s[NFEAT][NFEAT];
    __shared__ float tmp_s[NORB][NFEAT];
    __shared__ float G_s[NORB][NORB];
    __shared__ unsigned char m1_s[NCOL1];
    __shared__ int Ri_s[NORB], Rj_s[NORB], M_s;
    __shared__ double A1[NORB][NORB], A2[NORB][NORB];
    __shared__ double red_s[RPB / 64];
    __shared__ double det_s[2];
    __shared__ double h1sum_s;

    if (ch != 0) {
        // ---------------- two-body: wave-autonomous, no LDS, no barriers ----------------
        const int lane = tid & 63;
        const int r = (ch - 1) * RPB + tid;             // 0..1727
        const int i = r / 144, j = (r / NORB) % NORB, p = r % NORB;

        const float4* hr = (const float4*)(h2 + (size_t)t * NCOL2 + (size_t)r * NORB);
        const float4 ha = hr[0], hb = hr[1], hc = hr[2];

        int   xv  = 1;
        float psl = 0.f;
        if (lane < NORB) {
            xv = vn[t * NORB + lane];
            const float* pr = mfv + (size_t)t * NORB * NFEAT + lane * NFEAT;
            float s = 0.f;
            #pragma unroll
            for (int f = 0; f < NFEAT; ++f) s += pr[f];
            psl = s;
        }
        const unsigned long long bal = __ballot(xv == 2);
        const int X2  = (int)(bal & 0xFFFull);
        const int nx2 = ~X2 & 0xFFF;

        float sv = (lane < NORB) ? psl * (float)xv : 0.f;
        sv += __shfl_xor(sv, 8, 16);
        sv += __shfl_xor(sv, 4, 16);
        sv += __shfl_xor(sv, 2, 16);
        sv += __shfl_xor(sv, 1, 16);
        const float Sv = __shfl(sv, 0, 64);

        float psv[NORB];
        #pragma unroll
        for (int q = 0; q < NORB; ++q) psv[q] = __shfl(psl, q, 64);

        const int bi = 1 << i, bj = 1 << j, bp = 1 << p;
        const int um0 = 0xFFF & ~(bi | bj | bp);
        const int xi = 1 + ((X2 >> i) & 1);
        const int xj = 1 + ((X2 >> j) & 1);
        const int xp = 1 + ((X2 >> p) & 1);
        const int basei = xi + 1 - ((bi >> j) & 1) - ((bi >> p) & 1);
        const int basej = xj + ((bj >> i) & 1) - 1 - ((bj >> p) & 1);
        const int basep = xp + ((bp >> i) & 1) - ((bp >> j) & 1) - 1;
        const float a2b = Sv + __shfl(psl, i, 64) - __shfl(psl, j, 64)
                        - __shfl(psl, p, 64);

        float acc = 0.f;
#define COLQ(q, hv) {                                                       \
        const int bq  = 1 << (q);                                           \
        const int um  = um0 & ~bq;                                          \
        const int hm1 = nx2 & um, hm2 = X2 & um;                            \
        int mn = hm1 ? 1 : (hm2 ? 2 : 9);                                   \
        int mx = hm2 ? 2 : (hm1 ? 1 : -9);                                  \
        const int iq = (bi >> (q)) & 1, jq = (bj >> (q)) & 1,               \
                  pq = (bp >> (q)) & 1;                                     \
        const int vi = basei + iq, vj = basej + jq, vp = basep + pq;        \
        const int xq = 1 + ((X2 >> (q)) & 1);                               \
        const int vq = xq + 1 + iq - jq - pq;                               \
        mn = min(min(mn, vi), min(vj, min(vp, vq)));                        \
        mx = max(max(mx, vi), max(vj, max(vp, vq)));                        \
        const bool ok = (mx - mn == 1) && ((hv) > 0.0f);                    \
        const float tq = ok ? (hv) * (a2b + psv[q]) : 0.0f;                 \
        acc = fmaf(tq, tq, acc);                                            \
    }
        COLQ(0,  ha.x)  COLQ(1,  ha.y)  COLQ(2,  ha.z)  COLQ(3,  ha.w)
        COLQ(4,  hb.x)  COLQ(5,  hb.y)  COLQ(6,  hb.z)  COLQ(7,  hb.w)
        COLQ(8,  hc.x)  COLQ(9,  hc.y)  COLQ(10, hc.z)  COLQ(11, hc.w)
#undef COLQ

        double accd = (double)acc;
        #pragma unroll
        for (int o = 32; o > 0; o >>= 1) accd += __shfl_down(accd, o, 64);
        if (lane == 0) atomicAdd(&e2acc[t], accd);   // coherent point, 256 addrs
    } else {
        // ---------------- prep: G, one-body, determinants (LDS path) ----------------
        if (tid < NORB * NFEAT)
            phi_s[tid / NFEAT][tid % NFEAT] = mfv[(size_t)t * NORB * NFEAT + tid];
        if (tid >= NORB * NFEAT && tid < NORB * NFEAT + NORB)
            x_s[tid - NORB * NFEAT] = vn[t * NORB + (tid - NORB * NFEAT)];
        for (int k2 = tid; k2 < NFEAT * NFEAT; k2 += RPB) {
            int r2 = k2 / NFEAT, c2 = k2 % NFEAT;
            W_s[r2][c2] = w[k2] + w[c2 * NFEAT + r2];
        }
        __syncthreads();

        int X2 = 0;
        #pragma unroll
        for (int a = 0; a < NORB; ++a) X2 |= (x_s[a] == 2) ? (1 << a) : 0;
        const int nx2 = ~X2 & 0xFFF;

        if (tid < NORB * NFEAT) {
            int a = tid / NFEAT, f = tid % NFEAT;
            float s = 0.f;
            #pragma unroll
            for (int g = 0; g < NFEAT; ++g) s += phi_s[a][g] * W_s[g][f];
            tmp_s[a][f] = s;
        }
        __syncthreads();
        if (tid < NCOL1) {
            int a = tid / NORB, i = tid % NORB;
            float s = 0.f;
            #pragma unroll
            for (int f = 0; f < NFEAT; ++f) s += tmp_s[a][f] * phi_s[i][f];
            G_s[a][i] = s;
        }

        // one-body mask + h1^2 sum
        double h1c = 0.0;
        if (tid < NCOL1) {
            int ii = tid / NORB, jj = tid % NORB;
            int um  = 0xFFF & ~((1 << ii) | (1 << jj));
            int hm1 = nx2 & um, hm2 = X2 & um;
            int mn = hm1 ? 1 : (hm2 ? 2 : 9);
            int mx = hm2 ? 2 : (hm1 ? 1 : -9);
            int d  = (ii == jj) ? 0 : 1;
            int vi = x_s[ii] - d, vj = x_s[jj] + d;
            mn = min(mn, min(vi, vj));
            mx = max(mx, max(vi, vj));
            float h1v = h1[(size_t)t * NCOL1 + tid];
            bool ok = (mx - mn == 1) && (h1v > 0.0f);
            m1_s[tid] = ok ? 1 : 0;
            if (ok) h1c = (double)h1v * (double)h1v;
        }
        __syncthreads();
        {
            #pragma unroll
            for (int o = 32; o > 0; o >>= 1) h1c += __shfl_down(h1c, o, 64);
            const int wvv = tid >> 6, lane = tid & 63;
            if (lane == 0) red_s[wvv] = h1c;
            __syncthreads();
            if (tid == 0) h1sum_s = red_s[0] + red_s[1] + red_s[2];
        }

        if (tid < NORB) {
            int ri = 0, rj = 0;
            #pragma unroll
            for (int o = 0; o < NORB; ++o) {
                ri += m1_s[tid * NORB + o];
                rj += m1_s[o * NORB + tid];
            }
            Ri_s[tid] = ri;
            Rj_s[tid] = rj;
        }
        __syncthreads();
        if (tid == 0) {
            int m = 0;
            #pragma unroll
            for (int o = 0; o < NORB; ++o) m += Ri_s[o];
            M_s = m;
        }
        __syncthreads();

        if (tid < NCOL1) {
            int a = tid / NORB, b = tid % NORB;
            int xa = x_s[a], xb = x_s[b];
            int Da = Rj_s[a] - Ri_s[a], Db = Rj_s[b] - Ri_s[b];
            int s1 = xa * xb * M_s + xa * Db + xb * Da
                   - (int)m1_s[b * NORB + a] - (int)m1_s[a * NORB + b];
            if (a == b) s1 += Rj_s[a] + Ri_s[a];
            A1[a][b] = (double)G_s[a][b] * (double)s1;
            A2[a][b] = (double)G_s[a][b];
        }
        __syncthreads();

        // barrier-free in-register LU with partial pivoting; wave0: A1, wave1: A2
        const int wvv = tid >> 6, lane = tid & 63;
        if (wvv < 2) {
            const double* Abase = (wvv == 0) ? &A1[0][0] : &A2[0][0];
            const int rl = (lane < NORB) ? lane : 0;
            double a[NORB];
            #pragma unroll
            for (int c = 0; c < NORB; ++c) a[c] = Abase[rl * NORB + c];
            double det = 1.0;
            #pragma unroll
            for (int k = 0; k < NORB; ++k) {
                double key = (lane >= k && lane < NORB) ? fabs(a[k]) : -1.0;
                int idx = lane;
                #pragma unroll
                for (int off = 8; off >= 1; off >>= 1) {
                    double k2 = __shfl_xor(key, off);
                    int    i2 = __shfl_xor(idx, off);
                    if (k2 > key || (k2 == key && i2 < idx)) { key = k2; idx = i2; }
                }
                int pr = idx;
                if (pr != k) det = -det;
                int src = (lane == k) ? pr : ((lane == pr) ? k : lane);
                #pragma unroll
                for (int c = 0; c < NORB; ++c) a[c] = __shfl(a[c], src);
                double pk[NORB];
                #pragma unroll
                for (int c = 0; c < NORB; ++c) pk[c] = __shfl(a[c], k);
                double piv = pk[k];
                det *= piv;
                double inv = (piv != 0.0) ? 1.0 / piv : 0.0;
                double f = (lane > k && lane < NORB) ? a[k] * inv : 0.0;
                #pragma unroll
                for (int c = 0; c < NORB; ++c) a[c] = fma(-f, pk[c], a[c]);
            }
            if (lane == 0) det_s[wvv] = det;
        }
        __syncthreads();

        if (tid == 0) {
            double e1 = det_s[0] * det_s[0] * h1sum_s;
            int n2 = __popc(X2);
            double pd = det_s[1] * (double)(1ull << (2 * n2));
            __hip_atomic_store(&ep[2 * t], e1, __ATOMIC_RELAXED, __HIP_MEMORY_SCOPE_AGENT);
            __hip_atomic_store(&ep[2 * t + 1], pd * pd, __ATOMIC_RELAXED, __HIP_MEMORY_SCOPE_AGENT);
        }
    }

    // ---------------- hierarchical fence-free finalize ----------------
    // per-wave: wait own atomics/stores reached the coherence point (no cache flush)
    asm volatile("s_waitcnt vmcnt(0)" ::: "memory");
    __syncthreads();   // all waves of this block completed their global ops
    if (tid == 0) {
        unsigned old = __hip_atomic_fetch_add(&sctr[t], 1u, __ATOMIC_RELAXED,
                                              __HIP_MEMORY_SCOPE_AGENT);
        if (old == CPS - 1) {
            // sample finisher: all 10 blocks of sample t are complete
            double e2 = __hip_atomic_load(&e2acc[t], __ATOMIC_RELAXED,
                                          __HIP_MEMORY_SCOPE_AGENT);
            double e1 = __hip_atomic_load(&ep[2 * t], __ATOMIC_RELAXED,
                                          __HIP_MEMORY_SCOPE_AGENT);
            double p  = __hip_atomic_load(&ep[2 * t + 1], __ATOMIC_RELAXED,
                                          __HIP_MEMORY_SCOPE_AGENT);
            double e = e1 + e2;
            const int b = t >> 4;
            __hip_atomic_fetch_add(&sb_e[b], e * p, __ATOMIC_RELAXED,
                                   __HIP_MEMORY_SCOPE_AGENT);
            __hip_atomic_fetch_add(&sb_p[b], p, __ATOMIC_RELAXED,
                                   __HIP_MEMORY_SCOPE_AGENT);
            asm volatile("s_waitcnt vmcnt(0)" ::: "memory");
            unsigned ob = __hip_atomic_fetch_add(&bctr[b], 1u, __ATOMIC_RELAXED,
                                                 __HIP_MEMORY_SCOPE_AGENT);
            if (ob == NB - 1) {
                // batch finisher: all 16 samples of batch b folded
                double se = __hip_atomic_load(&sb_e[b], __ATOMIC_RELAXED,
                                              __HIP_MEMORY_SCOPE_AGENT);
                double sp = __hip_atomic_load(&sb_p[b], __ATOMIC_RELAXED,
                                              __HIP_MEMORY_SCOPE_AGENT);
                out[b] = (float)(se / sp);
            }
        }
    }
}

extern "C" void kernel_launch(void* const* d_in, const int* in_sizes, int n_in,
                              void* d_out, int out_size, void* d_ws, size_t ws_size,
                              hipStream_t stream) {
    const float* mfv = (const float*)d_in[0];
    const float* h1  = (const float*)d_in[1];
    const float* h2  = (const float*)d_in[2];
    const int*   vn  = (const int*)d_in[3];
    const float* w   = (const float*)d_in[4];
    float* out = (float*)d_out;

    // zeroed region (one small memset node per replay):
    //   [sctr u32*256 @0][bctr u32*16 @1024][e2acc dbl*256 @1088]
    //   [sb_e dbl*16 @3136][sb_p dbl*16 @3264]  -> 3392 bytes
    // non-zeroed (fully overwritten): ep dbl*512 @4096
    unsigned* sctr  = (unsigned*)d_ws;
    unsigned* bctr  = (unsigned*)((char*)d_ws + 1024);
    double*   e2acc = (double*)((char*)d_ws + 1088);
    double*   sb_e  = (double*)((char*)d_ws + 3136);
    double*   sb_p  = (double*)((char*)d_ws + 3264);
    double*   ep    = (double*)((char*)d_ws + 4096);

    hipMemsetAsync(d_ws, 0, 3392, stream);   // capture-legal memset node
    hipLaunchKernelGGL(eloc_one, dim3(GRID), dim3(RPB), 0, stream,
                       mfv, h1, h2, vn, w, sctr, bctr, e2acc, sb_e, sb_p, ep, out);
}

// Round 9
// 24.674 us; speedup vs baseline: 2.2758x; 1.3209x over previous
//
#include <hip/hip_runtime.h>

#define NORB   12
#define NFEAT  14
#define NCOL1  144
#define NCOL2  20736
#define NROWS  1728        // NORB^3 q-rows per sample
#define NSPLIT 9           // blocks per sample for two-body
#define RPB    192         // rows per two-body block (= block size)
#define BLKA   256

// Block-wide double reduction over 256 threads. Valid on thread 0 only.
__device__ inline double block_reduce_d(double v, double* red, int tid) {
    #pragma unroll
    for (int o = 32; o > 0; o >>= 1) v += __shfl_down(v, o, 64);
    if ((tid & 63) == 0) red[tid >> 6] = v;
    __syncthreads();
    double r = 0.0;
    if (tid == 0) {
        #pragma unroll
        for (int wv = 0; wv < BLKA / 64; ++wv) r += red[wv];
    }
    __syncthreads();
    return r;
}

// ---------------- Kernel A: per-sample prep + one-body + determinants ----------------
extern "C" __global__ void __launch_bounds__(BLKA)
eloc_prep(const float* __restrict__ mfv, const float* __restrict__ h1,
          const int* __restrict__ vn, const float* __restrict__ w,
          double* __restrict__ ep, float* __restrict__ prep)
{
    const int t   = blockIdx.x;
    const int tid = threadIdx.x;

    __shared__ float phi_s[NORB][NFEAT];
    __shared__ float W_s[NFEAT][NFEAT];
    __shared__ float tmp_s[NORB][NFEAT];
    __shared__ float G_s[NORB][NORB];
    __shared__ float ps_s[NORB];
    __shared__ int   x_s[NORB];
    __shared__ float Sv_s;
    __shared__ unsigned char m1_s[NCOL1];
    __shared__ int Ri_s[NORB], Rj_s[NORB], M_s;
    __shared__ double A1[NORB][NORB];
    __shared__ double A2[NORB][NORB];
    __shared__ double red_s[BLKA / 64];
    __shared__ double det_s[2];
    __shared__ double h1sum_s;

    // ---- stage ----
    if (tid < NORB * NFEAT) phi_s[tid / NFEAT][tid % NFEAT] = mfv[(size_t)t * NORB * NFEAT + tid];
    if (tid < NFEAT * NFEAT) {
        int r = tid / NFEAT, c = tid % NFEAT;
        W_s[r][c] = w[r * NFEAT + c] + w[c * NFEAT + r];
    }
    if (tid < NORB) x_s[tid] = vn[t * NORB + tid];
    __syncthreads();

    // ---- ps, phi @ Wsym ----
    if (tid < NORB) {
        float s = 0.f;
        #pragma unroll
        for (int f = 0; f < NFEAT; ++f) s += phi_s[tid][f];
        ps_s[tid] = s;
    }
    if (tid < NORB * NFEAT) {
        int a = tid / NFEAT, f = tid % NFEAT;
        float s = 0.f;
        #pragma unroll
        for (int g = 0; g < NFEAT; ++g) s += phi_s[a][g] * W_s[g][f];
        tmp_s[a][f] = s;
    }
    __syncthreads();

    if (tid < NCOL1) {
        int a = tid / NORB, i = tid % NORB;
        float s = 0.f;
        #pragma unroll
        for (int f = 0; f < NFEAT; ++f) s += tmp_s[a][f] * phi_s[i][f];
        G_s[a][i] = s;
    }
    if (tid == 0) {
        float s = 0.f;
        for (int a = 0; a < NORB; ++a) s += ps_s[a] * (float)x_s[a];
        Sv_s = s;
    }
    __syncthreads();

    int X2 = 0;
    #pragma unroll
    for (int a = 0; a < NORB; ++a) X2 |= (x_s[a] == 2) ? (1 << a) : 0;
    const int nx2 = ~X2 & 0xFFF;

    // ---- write per-sample prep struct for the two-body kernel ----
    if (tid < NORB)  prep[t * 16 + tid] = ps_s[tid];
    if (tid == NORB) prep[t * 16 + 12]  = Sv_s;
    if (tid == NORB + 1) prep[t * 16 + 13] = __int_as_float(X2);

    // ---- one-body mask (bit trick) + h1 sum ----
    double h1c = 0.0;
    if (tid < NCOL1) {
        int ii = tid / NORB, jj = tid % NORB;
        int um  = 0xFFF & ~((1 << ii) | (1 << jj));
        int hm1 = nx2 & um, hm2 = X2 & um;
        int mn = hm1 ? 1 : (hm2 ? 2 : 9);
        int mx = hm2 ? 2 : (hm1 ? 1 : -9);
        int d  = (ii == jj) ? 0 : 1;
        int vi = x_s[ii] - d, vj = x_s[jj] + d;
        mn = min(mn, min(vi, vj));
        mx = max(mx, max(vi, vj));
        float h1v = h1[(size_t)t * NCOL1 + tid];
        bool ok = (mx - mn == 1) && (h1v > 0.0f);
        m1_s[tid] = ok ? 1 : 0;
        if (ok) h1c = (double)h1v * (double)h1v;
    }
    __syncthreads();
    double h1sum = block_reduce_d(h1c, red_s, tid);
    if (tid == 0) h1sum_s = h1sum;

    // ---- row/col sums of the valid-pair matrix V (=m1) ----
    if (tid < NORB) {
        int ri = 0, rj = 0;
        #pragma unroll
        for (int o = 0; o < NORB; ++o) {
            ri += m1_s[tid * NORB + o];   // ii = tid
            rj += m1_s[o * NORB + tid];   // jj = tid
        }
        Ri_s[tid] = ri;
        Rj_s[tid] = rj;
    }
    __syncthreads();
    if (tid == 0) {
        int m = 0;
        #pragma unroll
        for (int o = 0; o < NORB; ++o) m += Ri_s[o];
        M_s = m;
    }
    __syncthreads();

    // ---- A1 = G .* S1 (analytic O(1) per entry), A2 = G ----
    if (tid < NCOL1) {
        int a = tid / NORB, b = tid % NORB;
        int xa = x_s[a], xb = x_s[b];
        int Da = Rj_s[a] - Ri_s[a], Db = Rj_s[b] - Ri_s[b];
        int s1 = xa * xb * M_s + xa * Db + xb * Da
               - (int)m1_s[b * NORB + a] - (int)m1_s[a * NORB + b];
        if (a == b) s1 += Rj_s[a] + Ri_s[a];
        A1[a][b] = (double)G_s[a][b] * (double)s1;
        A2[a][b] = (double)G_s[a][b];
    }
    __syncthreads();

    // ---- barrier-free in-register LU with partial pivoting; wave0: A1, wave1: A2 ----
    const int wv = tid >> 6, lane = tid & 63;
    if (wv < 2) {
        const double* Abase = (wv == 0) ? &A1[0][0] : &A2[0][0];
        const int rl = (lane < NORB) ? lane : 0;
        double a[NORB];
        #pragma unroll
        for (int c = 0; c < NORB; ++c) a[c] = Abase[rl * NORB + c];
        double det = 1.0;
        #pragma unroll
        for (int k = 0; k < NORB; ++k) {
            double key = (lane >= k && lane < NORB) ? fabs(a[k]) : -1.0;
            int idx = lane;
            #pragma unroll
            for (int off = 8; off >= 1; off >>= 1) {
                double k2 = __shfl_xor(key, off);
                int    i2 = __shfl_xor(idx, off);
                if (k2 > key || (k2 == key && i2 < idx)) { key = k2; idx = i2; }
            }
            int pr = idx;
            if (pr != k) det = -det;
            int src = (lane == k) ? pr : ((lane == pr) ? k : lane);
            #pragma unroll
            for (int c = 0; c < NORB; ++c) a[c] = __shfl(a[c], src);
            double pk[NORB];
            #pragma unroll
            for (int c = 0; c < NORB; ++c) pk[c] = __shfl(a[c], k);
            double piv = pk[k];
            det *= piv;
            double inv = (piv != 0.0) ? 1.0 / piv : 0.0;
            double f = (lane > k && lane < NORB) ? a[k] * inv : 0.0;
            #pragma unroll
            for (int c = 0; c < NORB; ++c) a[c] = fma(-f, pk[c], a[c]);
        }
        if (lane == 0) det_s[wv] = det;
    }
    __syncthreads();

    if (tid == 0) {
        double e1 = det_s[0] * det_s[0] * h1sum_s;
        int n2 = __popc(X2);
        double pd = det_s[1] * (double)(1ull << (2 * n2));
        ep[2 * t]     = e1;        // e2 added in the final kernel
        ep[2 * t + 1] = pd * pd;
    }
}

// ---------------- Kernel B: two-body partial sums ----------------
extern "C" __global__ void __launch_bounds__(RPB)
eloc_2body(const float* __restrict__ h2, const float* __restrict__ prep,
           double* __restrict__ part)
{
    const int tid = threadIdx.x;
    const int t   = blockIdx.x / NSPLIT;
    const int ch  = blockIdx.x % NSPLIT;

    __shared__ float ps_s[NORB];
    __shared__ double red_s[RPB / 64];

    if (tid < NORB) ps_s[tid] = prep[t * 16 + tid];
    __syncthreads();

    // uniform per-sample constants (block-uniform address -> scalar loads)
    const float4* pp = (const float4*)(prep + t * 16);
    const float4 u0 = pp[0], u1 = pp[1], u2 = pp[2], u3 = pp[3];
    const float Sv  = u3.x;
    const int   x2m = __float_as_int(u3.y);
    const int   nx2 = ~x2m & 0xFFF;

    const int r = ch * RPB + tid;                 // 0..1727
    const int i = r / 144, j = (r / NORB) % NORB, p = r % NORB;

    const float4* hr = (const float4*)(h2 + (size_t)t * NCOL2 + (size_t)r * NORB);
    const float4 ha = hr[0], hb = hr[1], hc = hr[2];

    const int bi = 1 << i, bj = 1 << j, bp = 1 << p;
    const int um0 = 0xFFF & ~(bi | bj | bp);
    const int xi = 1 + ((x2m >> i) & 1);
    const int xj = 1 + ((x2m >> j) & 1);
    const int xp = 1 + ((x2m >> p) & 1);
    const int basei = xi + 1 - ((bi >> j) & 1) - ((bi >> p) & 1);
    const int basej = xj + ((bj >> i) & 1) - 1 - ((bj >> p) & 1);
    const int basep = xp + ((bp >> i) & 1) - ((bp >> j) & 1) - 1;
    const float a2b = Sv + ps_s[i] - ps_s[j] - ps_s[p];

    float acc = 0.f;
#define COLQ(q, hv, psq) {                                                  \
        const int bq  = 1 << (q);                                           \
        const int um  = um0 & ~bq;                                          \
        const int hm1 = nx2 & um, hm2 = x2m & um;                           \
        int mn = hm1 ? 1 : (hm2 ? 2 : 9);                                   \
        int mx = hm2 ? 2 : (hm1 ? 1 : -9);                                  \
        const int iq = (bi >> (q)) & 1, jq = (bj >> (q)) & 1,               \
                  pq = (bp >> (q)) & 1;                                     \
        const int vi = basei + iq, vj = basej + jq, vp = basep + pq;        \
        const int xq = 1 + ((x2m >> (q)) & 1);                              \
        const int vq = xq + 1 + iq - jq - pq;                               \
        mn = min(min(mn, vi), min(vj, min(vp, vq)));                        \
        mx = max(max(mx, vi), max(vj, max(vp, vq)));                        \
        const bool ok = (mx - mn == 1) && ((hv) > 0.0f);                    \
        const float tq = ok ? (hv) * (a2b + (psq)) : 0.0f;                  \
        acc = fmaf(tq, tq, acc);                                            \
    }
    COLQ(0,  ha.x, u0.x)  COLQ(1,  ha.y, u0.y)  COLQ(2,  ha.z, u0.z)
    COLQ(3,  ha.w, u0.w)  COLQ(4,  hb.x, u1.x)  COLQ(5,  hb.y, u1.y)
    COLQ(6,  hb.z, u1.z)  COLQ(7,  hb.w, u1.w)  COLQ(8,  hc.x, u2.x)
    COLQ(9,  hc.y, u2.y)  COLQ(10, hc.z, u2.z)  COLQ(11, hc.w, u2.w)
#undef COLQ

    double accd = (double)acc;
    #pragma unroll
    for (int o = 32; o > 0; o >>= 1) accd += __shfl_down(accd, o, 64);
    const int lane = tid & 63, wv = tid >> 6;
    if (lane == 0) red_s[wv] = accd;
    __syncthreads();
    if (tid == 0) part[blockIdx.x] = red_s[0] + red_s[1] + red_s[2];
}

// ---------------- Kernel C: combine ----------------
extern "C" __global__ void __launch_bounds__(256)
eloc_final(const double* __restrict__ ep, const double* __restrict__ part,
           float* __restrict__ out, int T)
{
    const int s = threadIdx.x;
    __shared__ double se_s[256], sp_s[256];
    if (s < T) {
        double e2 = 0.0;
        #pragma unroll
        for (int k = 0; k < NSPLIT; ++k) e2 += part[s * NSPLIT + k];
        double e = ep[2 * s] + e2;
        double p = ep[2 * s + 1];
        se_s[s] = e * p;
        sp_s[s] = p;
    }
    __syncthreads();
    if (s < T / 16) {
        double se = 0.0, sp = 0.0;
        #pragma unroll
        for (int u = 0; u < 16; ++u) { se += se_s[s * 16 + u]; sp += sp_s[s * 16 + u]; }
        out[s] = (float)(se / sp);
    }
}

extern "C" void kernel_launch(void* const* d_in, const int* in_sizes, int n_in,
                              void* d_out, int out_size, void* d_ws, size_t ws_size,
                              hipStream_t stream) {
    const float* mfv = (const float*)d_in[0];
    const float* h1  = (const float*)d_in[1];
    const float* h2  = (const float*)d_in[2];
    const int*   vn  = (const int*)d_in[3];
    const float* w   = (const float*)d_in[4];
    float* out = (float*)d_out;

    const int T = in_sizes[0] / (NORB * NFEAT);   // 256

    double* ep   = (double*)d_ws;                 // 2T doubles
    double* part = ep + 2 * T;                    // NSPLIT*T doubles
    float*  prep = (float*)(part + NSPLIT * T);   // 16T floats

    hipLaunchKernelGGL(eloc_prep, dim3(T), dim3(BLKA), 0, stream,
                       mfv, h1, vn, w, ep, prep);
    hipLaunchKernelGGL(eloc_2body, dim3(T * NSPLIT), dim3(RPB), 0, stream,
                       h2, prep, part);
    hipLaunchKernelGGL(eloc_final, dim3(1), dim3(256), 0, stream, ep, part, out, T);
}